// Round 2
// baseline (385.040 us; speedup 1.0000x reference)
//
#include <hip/hip_runtime.h>
#include <cstdint>

#define NCOLS  696     // 16 + 120 + 560 subsets of size <= 3, bitmask order
#define NGROUP 174     // NCOLS / 4
#define NREC   136     // 16 singles + 120 pairs
#define RPB    4       // rows per block (one wave per row)
#define BLOCK  256

typedef float v4f __attribute__((ext_vector_type(4)));

// Record id: single a -> a ; pair (a<b) -> 16 + b*(b-1)/2 + a.
constexpr int pr(int a, int b) { return 16 + b * (b - 1) / 2 + a; }

// Per-record source operands (lo | hi<<8): rec[r] = selpair(v[hi], v[lo]).
struct alignas(8) RecSrc { uint16_t d[NREC]; };
constexpr RecSrc make_recs() {
    RecSrc t{};
    for (int a = 0; a < 16; ++a) t.d[a] = (uint16_t)(a | (a << 8));
    int p = 16;
    for (int b = 1; b < 16; ++b)
        for (int a = 0; a < b; ++a)
            t.d[p++] = (uint16_t)(a | (b << 8));
    return t;
}

// Per-column descriptor (Lrec | Rrec<<8): out = selpair(rec[Lrec], rec[Rrec]).
struct alignas(8) ColTbl { uint16_t d[NCOLS]; };
constexpr ColTbl make_cols() {
    ColTbl t{};
    int p = 0;
    for (int h = 0; h < 16; ++h) {
        t.d[p++] = (uint16_t)(h | (h << 8));
        for (int j = 0; j < h; ++j) {
            int pjh = pr(j, h);
            t.d[p++] = (uint16_t)(pjh | (pjh << 8));
            for (int i = 0; i < j; ++i)
                t.d[p++] = (uint16_t)(pr(j, h) | (pr(i, j) << 8));
        }
    }
    return t;
}

__constant__ RecSrc g_recs = make_recs();
__constant__ ColTbl g_cols = make_cols();

// Tie-exact select. cur comparison uses the sum proxy: RN(0.5l+0.5u) =
// 0.5*RN(l+u) exactly (power-of-two scaling), so ==/> are preserved
// bit-for-bit vs the NumPy fp32 reference. Beta path kept in RN form.
__device__ __forceinline__ float2 selpair(float2 L, float2 R) {
    float curL = __fadd_rn(L.x, L.y);
    float curR = __fadd_rn(R.x, R.y);
    float bL = __fadd_rn(__fmul_rn(0.2f, L.x), __fmul_rn(0.8f, L.y));
    float bR = __fadd_rn(__fmul_rn(0.2f, R.x), __fmul_rn(0.8f, R.y));
    bool choose_right = (curL == curR) ? (bL > bR) : (curL > curR);
    return choose_right ? R : L;
}

__device__ __forceinline__ float2 col_compute(const float2* __restrict__ rec,
                                              uint32_t d) {
    float2 L = rec[d & 255u];
    float2 R = rec[(d >> 8) & 255u];
    return selpair(L, R);
}

// launch_bounds(256, 8): 8 waves/EU -> 8 blocks/CU (32 waves/CU). Forces the
// allocator to VGPR <= 64 so occupancy stays at the full 8 waves/SIMD band;
// worst-case live set in the column loop is ~45 VGPRs, so no spill expected.
__global__ __launch_bounds__(BLOCK, 8) void minint_kernel(
    const float* __restrict__ xl, const float* __restrict__ xu,
    float* __restrict__ out, int batch)
{
    __shared__ float2 vals[RPB][16];
    __shared__ float2 recs[RPB][NREC];
    const int t    = threadIdx.x;
    const int w    = t >> 6;   // wave id == local row
    const int lane = t & 63;
    const int row  = blockIdx.x * RPB + w;

    // Wave-private staging: each wave stages its OWN row; no block barriers.
    // DS pipe is in-order per wave; wave_barrier only blocks code motion.
    if (lane < 16) {
        vals[w][lane] = make_float2(xl[row * 16 + lane], xu[row * 16 + lane]);
    }
    __builtin_amdgcn_wave_barrier();

    const float2* v = vals[w];

    // 136 single/pair records for this wave's row.
    for (int r = lane; r < NREC; r += 64) {
        uint32_t s = g_recs.d[r];
        float2 lo = v[s & 15u];
        float2 hi = v[(s >> 8) & 15u];
        recs[w][r] = selpair(hi, lo);
    }
    __builtin_amdgcn_wave_barrier();

    const int rowg = row;
    const float2* rec = recs[w];
    float* outl = out + (size_t)rowg * NCOLS;
    float* outu = out + (size_t)batch * NCOLS + (size_t)rowg * NCOLS;
    const ushort4* cols = (const ushort4*)g_cols.d;

    // 174 groups of 4 columns; lane g handles columns [4g, 4g+4).
    // Row byte stride = 696*4 = 174*16 -> float4 stores stay 16B-aligned.
    // Regular (cached) stores: matches the poison-fill's proven 6.25 TB/s
    // path; output is write-once so L2 streaming/писeviction is harmless.
    for (int g = lane; g < NGROUP; g += 64) {
        ushort4 d4 = cols[g];
        float2 c0 = col_compute(rec, d4.x);
        float2 c1 = col_compute(rec, d4.y);
        float2 c2 = col_compute(rec, d4.z);
        float2 c3 = col_compute(rec, d4.w);
        v4f rl = { c0.x, c1.x, c2.x, c3.x };
        v4f ru = { c0.y, c1.y, c2.y, c3.y };
        *(v4f*)(outl + 4 * g) = rl;
        *(v4f*)(outu + 4 * g) = ru;
    }
}

extern "C" void kernel_launch(void* const* d_in, const int* in_sizes, int n_in,
                              void* d_out, int out_size, void* d_ws, size_t ws_size,
                              hipStream_t stream) {
    const float* xl = (const float*)d_in[0];
    const float* xu = (const float*)d_in[1];
    float* out = (float*)d_out;
    const int batch = in_sizes[0] / 16;          // 65536
    const int grid  = batch / RPB;               // 16384 blocks x 4 waves
    minint_kernel<<<grid, BLOCK, 0, stream>>>(xl, xu, out, batch);
}